// Round 2
// baseline (170.349 us; speedup 1.0000x reference)
//
#include <hip/hip_runtime.h>

// Problem constants: z(8,128,64,64) f32, codes(16,256,8) f32
// outputs: soft (8,64,64,128) f32, hard (8,64,64,128) f32, idx (8,64,64,16) int->f32
#define NPOS 32768   // B*W*H
#define CCH  128
#define LL   16
#define KK   256
#define CD   8

typedef float f32x2 __attribute__((ext_vector_type(2)));

__global__ __launch_bounds__(1024) void soft_hard_enc(
    const float* __restrict__ z, const float* __restrict__ codes,
    float* __restrict__ out)
{
    // LDS staging for transposed (channel-fastest) output writes
    __shared__ float s_soft[64][132];  // +4 pad keeps 16B row alignment
    __shared__ int   s_idx[64][17];

    const int tid = (int)threadIdx.x;
    const int p   = tid & 63;                                   // position within block
    const int l   = __builtin_amdgcn_readfirstlane(tid >> 6);   // wave-uniform latent
    const int posBase = (int)blockIdx.x * 64;
    const int pos = posBase + p;
    const int b   = pos >> 12;
    const int wh  = pos & 4095;

    // z[b][c][w][h], c = l*8 + cd : coalesced across lanes (consecutive wh)
    const float* zp = z + (((size_t)(b * CCH + l * CD)) << 12) + wh;
    f32x2 hv[CD / 2];
#pragma unroll
    for (int c = 0; c < CD / 2; ++c) {
        hv[c][0] = zp[((size_t)(2 * c)) << 12];
        hv[c][1] = zp[((size_t)(2 * c + 1)) << 12];
    }

    const float* __restrict__ cp = codes + (size_t)l * KK * CD; // uniform -> s_load

    f32x2 acc[CD / 2];
#pragma unroll
    for (int c = 0; c < CD / 2; ++c) acc[c] = (f32x2){0.0f, 0.0f};
    float ssum  = 0.0f;
    float bestd = 3.4e38f;
    int   bestk = 0;

#pragma unroll 8
    for (int k = 0; k < KK; ++k) {
        f32x2 cod[CD / 2];
#pragma unroll
        for (int c = 0; c < CD / 2; ++c)
            cod[c] = *(const f32x2*)&cp[k * CD + 2 * c];

        // packed squared distance: 4x v_pk_add (neg) + 4x v_pk_fma + 1 hadd
        f32x2 d2p = (f32x2){0.0f, 0.0f};
#pragma unroll
        for (int c = 0; c < CD / 2; ++c) {
            f32x2 df = hv[c] - cod[c];
            d2p = __builtin_elementwise_fma(df, df, d2p);
        }
        float d2 = d2p[0] + d2p[1];

        float dist = __builtin_amdgcn_sqrtf(d2);
        float e = __expf(-dist);        // dist>=0 -> exp<=1, no max-shift needed
        ssum += e;

        f32x2 ev = (f32x2){e, e};       // op_sel broadcast, 4x v_pk_fma
#pragma unroll
        for (int c = 0; c < CD / 2; ++c)
            acc[c] = __builtin_elementwise_fma(ev, cod[c], acc[c]);

        // strict < keeps first-occurrence like np.argmin; d2 monotone with dist
        if (d2 < bestd) { bestd = d2; bestk = k; }
    }

    const float inv = 1.0f / ssum;
#pragma unroll
    for (int c = 0; c < CD / 2; ++c) {
        s_soft[p][l * CD + 2 * c]     = acc[c][0] * inv;
        s_soft[p][l * CD + 2 * c + 1] = acc[c][1] * inv;
    }
    s_idx[p][l] = bestk;
    __syncthreads();

    // ---- output phase: coalesced float4 writes from LDS
    const int p2 = tid >> 4;   // 0..63
    const int l2 = tid & 15;   // 0..15
    const size_t obase = ((size_t)(posBase + p2)) * CCH + (size_t)(l2 * CD);

    float4 v0 = *(const float4*)&s_soft[p2][l2 * CD];
    float4 v1 = *(const float4*)&s_soft[p2][l2 * CD + 4];
    *(float4*)&out[obase]     = v0;
    *(float4*)&out[obase + 4] = v1;

    const int kb = s_idx[p2][l2];
    const float* hp = codes + ((size_t)(l2 * KK + kb)) * CD;   // cached gather
    float4 h0 = *(const float4*)&hp[0];
    float4 h1 = *(const float4*)&hp[4];
    float* outh = out + (size_t)NPOS * CCH;
    *(float4*)&outh[obase]     = h0;
    *(float4*)&outh[obase + 4] = h1;

    float* outi = out + (size_t)2 * NPOS * CCH;
    outi[(size_t)posBase * LL + tid] = (float)s_idx[tid >> 4][tid & 15];
}

extern "C" void kernel_launch(void* const* d_in, const int* in_sizes, int n_in,
                              void* d_out, int out_size, void* d_ws, size_t ws_size,
                              hipStream_t stream) {
    const float* z     = (const float*)d_in[0];
    const float* codes = (const float*)d_in[1];
    float* out = (float*)d_out;
    soft_hard_enc<<<dim3(NPOS / 64), dim3(1024), 0, stream>>>(z, codes, out);
}

// Round 3
// 152.356 us; speedup vs baseline: 1.1181x; 1.1181x over previous
//
#include <hip/hip_runtime.h>

// z(8,128,64,64) f32, codes(16,256,8) f32
// out: soft(8,64,64,128) | hard(8,64,64,128) | idx(8,64,64,16) as f32
#define NPOS 32768
#define CCH  128
#define LL   16
#define KK   256
#define CD   8

typedef float f32x2 __attribute__((ext_vector_type(2)));

#if __has_builtin(__builtin_amdgcn_exp2f)
#define EXP2NEG(x) __builtin_amdgcn_exp2f(-(x))
#else
#define EXP2NEG(x) __expf(-0.6931471805599453f * (x))
#endif

#define SQS    1.2011224087864498f   // sqrt(log2(e)) : pre-scale so exp2(-sqrt(d2')) == exp(-dist)
#define INVSQS 0.8325546111576977f   // 1/SQS : un-scale the soft accumulation

__global__ __launch_bounds__(512) void soft_hard_enc(
    const float* __restrict__ z, const float* __restrict__ codes,
    float* __restrict__ out)
{
    // 4 latents x 128 pairs x 16 floats: [e_c0,o_c0,e_c1,o_c1,...] pre-scaled by SQS
    __shared__ float s_codes[4 * 2048];   // 32 KB

    const int tid = (int)threadIdx.x;
    const int bid = (int)blockIdx.x;
    const int posBase = (bid >> 2) * 128;
    const int lBase   = (bid & 3) * 4;

    // ---- one-time: stage codes pair-interleaved + scaled (coalesced 64B/thread reads)
    {
        const int ll = tid >> 7;          // 0..3
        const int j  = tid & 127;         // pair index
        const float* g = codes + ((size_t)((lBase + ll) * KK + 2 * j)) * CD;
        float4 q0 = *(const float4*)(g + 0);   // even code c0..c3
        float4 q1 = *(const float4*)(g + 4);   // even c4..c7
        float4 q2 = *(const float4*)(g + 8);   // odd  c0..c3
        float4 q3 = *(const float4*)(g + 12);  // odd  c4..c7
        float* d = s_codes + ll * 2048 + j * 16;
        ((float4*)d)[0] = (float4){SQS*q0.x, SQS*q2.x, SQS*q0.y, SQS*q2.y};
        ((float4*)d)[1] = (float4){SQS*q0.z, SQS*q2.z, SQS*q0.w, SQS*q2.w};
        ((float4*)d)[2] = (float4){SQS*q1.x, SQS*q3.x, SQS*q1.y, SQS*q3.y};
        ((float4*)d)[3] = (float4){SQS*q1.z, SQS*q3.z, SQS*q1.w, SQS*q3.w};
    }

    const int l   = tid >> 7;             // wave-uniform latent (2 waves per l)
    const int p   = tid & 127;
    const int pos = posBase + p;
    const int b   = pos >> 12;
    const int wh  = pos & 4095;
    const int l4  = lBase + l;

    // hv load (coalesced per channel), scaled, broadcast into pairs
    const float* zp = z + (((size_t)(b * CCH + l4 * CD)) << 12) + wh;
    f32x2 hvp[CD];
#pragma unroll
    for (int c = 0; c < CD; ++c) {
        float v = SQS * zp[((size_t)c) << 12];
        hvp[c] = (f32x2){v, v};
    }

    __syncthreads();

    const float4* cb = (const float4*)(s_codes + l * 2048);

    f32x2 acc[CD];
#pragma unroll
    for (int c = 0; c < CD; ++c) acc[c] = (f32x2){0.f, 0.f};
    f32x2 ssump = (f32x2){0.f, 0.f};
    float bd0 = 3.4e38f, bd1 = 3.4e38f;
    int   bj0 = 0,       bj1 = 0;

#pragma unroll 4
    for (int j = 0; j < KK / 2; ++j) {
        float4 q0 = cb[j * 4 + 0];     // wave-uniform addr -> LDS broadcast
        float4 q1 = cb[j * 4 + 1];
        float4 q2 = cb[j * 4 + 2];
        float4 q3 = cb[j * 4 + 3];
        f32x2 cp[CD] = {
            {q0.x, q0.y}, {q0.z, q0.w}, {q1.x, q1.y}, {q1.z, q1.w},
            {q2.x, q2.y}, {q2.z, q2.w}, {q3.x, q3.y}, {q3.z, q3.w}};

        f32x2 d2p = (f32x2){0.f, 0.f};   // (scaled d2 even, scaled d2 odd)
#pragma unroll
        for (int c = 0; c < CD; ++c) {
            f32x2 df = hvp[c] - cp[c];
            d2p = __builtin_elementwise_fma(df, df, d2p);
        }
        float e0 = EXP2NEG(__builtin_amdgcn_sqrtf(d2p[0]));
        float e1 = EXP2NEG(__builtin_amdgcn_sqrtf(d2p[1]));
        f32x2 ep = (f32x2){e0, e1};
        ssump += ep;
#pragma unroll
        for (int c = 0; c < CD; ++c)
            acc[c] = __builtin_elementwise_fma(ep, cp[c], acc[c]);

        // per-parity argmin, strict < = first occurrence within parity
        if (d2p[0] < bd0) { bd0 = d2p[0]; bj0 = j; }
        if (d2p[1] < bd1) { bd1 = d2p[1]; bj1 = j; }
    }

    // merge parities; exact-tie -> smaller k (np.argmin first occurrence)
    int ke = 2 * bj0, ko = 2 * bj1 + 1;
    int bestk = ke;
    if (bd1 < bd0 || (bd1 == bd0 && ko < ke)) bestk = ko;

    const float ssum = ssump[0] + ssump[1];
    const float sc   = INVSQS / ssum;    // un-scale + softmax normalize

    float a0 = (acc[0][0] + acc[0][1]) * sc;
    float a1 = (acc[1][0] + acc[1][1]) * sc;
    float a2 = (acc[2][0] + acc[2][1]) * sc;
    float a3 = (acc[3][0] + acc[3][1]) * sc;
    float a4 = (acc[4][0] + acc[4][1]) * sc;
    float a5 = (acc[5][0] + acc[5][1]) * sc;
    float a6 = (acc[6][0] + acc[6][1]) * sc;
    float a7 = (acc[7][0] + acc[7][1]) * sc;

    const size_t obase = (size_t)pos * CCH + (size_t)(l4 * CD);
    *(float4*)&out[obase]     = (float4){a0, a1, a2, a3};
    *(float4*)&out[obase + 4] = (float4){a4, a5, a6, a7};

    // hard: gather un-scaled code from global (L2-hot 128 KB)
    const float* hp = codes + ((size_t)(l4 * KK + bestk)) * CD;
    float4 h0 = *(const float4*)(hp + 0);
    float4 h1 = *(const float4*)(hp + 4);
    float* outh = out + (size_t)NPOS * CCH;
    *(float4*)&outh[obase]     = h0;
    *(float4*)&outh[obase + 4] = h1;

    float* outi = out + (size_t)2 * NPOS * CCH;
    outi[(size_t)pos * LL + l4] = (float)bestk;
}

extern "C" void kernel_launch(void* const* d_in, const int* in_sizes, int n_in,
                              void* d_out, int out_size, void* d_ws, size_t ws_size,
                              hipStream_t stream) {
    const float* z     = (const float*)d_in[0];
    const float* codes = (const float*)d_in[1];
    float* out = (float*)d_out;
    soft_hard_enc<<<dim3((NPOS / 128) * 4), dim3(512), 0, stream>>>(z, codes, out);
}